// Round 5
// baseline (315.335 us; speedup 1.0000x reference)
//
#include <hip/hip_runtime.h>

#define DD 128
#define NN 50000      // nodes (N)
#define BB 2          // batch
#define EE 500000     // edges
#define LN_EPS 1e-5f

typedef __attribute__((ext_vector_type(8))) short bf16x8;
typedef __attribute__((ext_vector_type(16))) float f32x16;

union FragU { unsigned short u[8]; bf16x8 v; };

__device__ __forceinline__ unsigned short f2bf(float x) {
  union { float f; unsigned u; } v; v.f = x;
  unsigned r = (v.u + 0x7FFFu + ((v.u >> 16) & 1u)) >> 16;
  return (unsigned short)r;
}
__device__ __forceinline__ float bfbits(short s) {
  union { unsigned u; float f; } v;
  v.u = ((unsigned)(unsigned short)s) << 16;
  return v.f;
}
__device__ __forceinline__ float sigmoidf(float x) {
  return 1.0f / (1.0f + __expf(-x));
}

// ---------------------------------------------------------------------------
// k_prep: zero deg + convert rel_emb fp32 -> bf16 (relb[r][128]).
// ---------------------------------------------------------------------------
__global__ __launch_bounds__(256) void k_prep(
    const float* __restrict__ rel_emb, unsigned short* __restrict__ relb,
    int* __restrict__ deg)
{
  const int id = blockIdx.x * 256 + threadIdx.x;
  if (id < 500 * DD / 2) {
    const float a = rel_emb[2 * id];
    const float b = rel_emb[2 * id + 1];
    *(unsigned int*)&relb[2 * id] =
        (unsigned int)f2bf(a) | ((unsigned int)f2bf(b) << 16);
  }
  if (id < NN) deg[id] = 0;
}

// ---------------------------------------------------------------------------
// Kernel 1: node dual-GEMM, 32x32x16 MFMA, weights register-resident.
// Wave w of each block owns output features [32w, 32w+32); its A-frags
// (gate_W + msg_W strips) are loaded ONCE into VGPRs before the tile loop.
// Per 32-node tile: 16 global B-loads (h) + 16 MFMA. No LDS at all.
// D[f][node]: col=lane&31=node, row=(r&3)+8*(r>>2)+4*(lane>>5).
// ---------------------------------------------------------------------------
__global__ __launch_bounds__(256) void k_node(
    const float* __restrict__ h, const float* __restrict__ gate_W,
    const float* __restrict__ msg_W, unsigned short* __restrict__ P,
    unsigned short* __restrict__ hb, int BN)
{
  const int t    = threadIdx.x;
  const int w    = t >> 6;        // wave -> feature strip [32w, 32w+32)
  const int lane = t & 63;
  const int n32  = lane & 31;
  const int hi   = lane >> 5;
  const int f    = w * 32 + n32;  // A-operand row m

  // ---- A-frags, hoisted: A[m=f][k = 16ks + 8hi + j] ----
  FragU ag[8], am[8];
#pragma unroll
  for (int ks = 0; ks < 8; ks++) {
#pragma unroll
    for (int j = 0; j < 8; j++) {
      const int k = ks * 16 + hi * 8 + j;
      ag[ks].u[j] = f2bf(gate_W[k * DD + f]);
      am[ks].u[j] = f2bf(msg_W [k * DD + f]);
    }
  }

  const int nT = BN >> 5;   // 32-row tiles
  for (int tile = blockIdx.x; tile < nT; tile += gridDim.x) {
    const int row  = tile * 32 + n32;
    const size_t hoff = (size_t)row * DD + hi * 8;

    // B-frags: B[k][n=row], lane reads h[row][16ks + 8hi + 0..7]
    FragU bf[8];
#pragma unroll
    for (int ks = 0; ks < 8; ks++) {
      const float4 x0 = *(const float4*)(h + hoff + ks * 16);
      const float4 x1 = *(const float4*)(h + hoff + ks * 16 + 4);
      bf[ks].u[0] = f2bf(x0.x); bf[ks].u[1] = f2bf(x0.y);
      bf[ks].u[2] = f2bf(x0.z); bf[ks].u[3] = f2bf(x0.w);
      bf[ks].u[4] = f2bf(x1.x); bf[ks].u[5] = f2bf(x1.y);
      bf[ks].u[6] = f2bf(x1.z); bf[ks].u[7] = f2bf(x1.w);
    }
    // bf16 h copy: the 4 waves hold identical B data; split stores by wave
    *(bf16x8*)(hb + hoff + (2 * w)     * 16) = bf[2 * w].v;
    *(bf16x8*)(hb + hoff + (2 * w + 1) * 16) = bf[2 * w + 1].v;

    f32x16 accg = (f32x16)0.f, accm = (f32x16)0.f;
#pragma unroll
    for (int ks = 0; ks < 8; ks++) {
      accg = __builtin_amdgcn_mfma_f32_32x32x16_bf16(ag[ks].v, bf[ks].v, accg, 0, 0, 0);
      accm = __builtin_amdgcn_mfma_f32_32x32x16_bf16(am[ks].v, bf[ks].v, accm, 0, 0, 0);
    }

    // epilogue: P[node][b*128 + f], f = 32w + 8q + 4hi + i
    const int b    = (row >= NN) ? 1 : 0;
    const int node = row - b * NN;
    unsigned short* Pr = P + (size_t)node * 256 + b * 128 + w * 32 + hi * 4;
#pragma unroll
    for (int q = 0; q < 4; q++) {
      const float v0 = accm[q * 4 + 0] * sigmoidf(accg[q * 4 + 0]);
      const float v1 = accm[q * 4 + 1] * sigmoidf(accg[q * 4 + 1]);
      const float v2 = accm[q * 4 + 2] * sigmoidf(accg[q * 4 + 2]);
      const float v3 = accm[q * 4 + 3] * sigmoidf(accg[q * 4 + 3]);
      uint2 o;
      o.x = (unsigned int)f2bf(v0) | ((unsigned int)f2bf(v1) << 16);
      o.y = (unsigned int)f2bf(v2) | ((unsigned int)f2bf(v3) << 16);
      *(uint2*)(Pr + q * 8) = o;
    }
  }
}

// ---------------------------------------------------------------------------
// CSR build: histogram -> block scans -> fill (counting sort by target).
// ---------------------------------------------------------------------------
__global__ __launch_bounds__(256) void k_hist(
    const int* __restrict__ etgt, int* __restrict__ deg)
{
  const int e = blockIdx.x * 256 + threadIdx.x;
  if (e < EE) atomicAdd(&deg[etgt[e]], 1);
}

__global__ __launch_bounds__(256) void k_scan_block(
    const int* __restrict__ deg, int* __restrict__ rstart,
    int* __restrict__ bsum, int N)
{
  __shared__ int s[256];
  const int i = blockIdx.x * 256 + threadIdx.x;
  const int v = (i < N) ? deg[i] : 0;
  s[threadIdx.x] = v;
  __syncthreads();
#pragma unroll
  for (int off = 1; off < 256; off <<= 1) {
    const int tv = (threadIdx.x >= off) ? s[threadIdx.x - off] : 0;
    __syncthreads();
    s[threadIdx.x] += tv;
    __syncthreads();
  }
  if (i < N) rstart[i] = s[threadIdx.x] - v;
  if (threadIdx.x == 255) bsum[blockIdx.x] = s[255];
}

__global__ __launch_bounds__(256) void k_scan_small(
    int* __restrict__ bsum, int* __restrict__ boff, int nb)
{
  __shared__ int s[256];
  const int v = (threadIdx.x < nb) ? bsum[threadIdx.x] : 0;
  s[threadIdx.x] = v;
  __syncthreads();
#pragma unroll
  for (int off = 1; off < 256; off <<= 1) {
    const int tv = (threadIdx.x >= off) ? s[threadIdx.x - off] : 0;
    __syncthreads();
    s[threadIdx.x] += tv;
    __syncthreads();
  }
  if (threadIdx.x < nb) boff[threadIdx.x] = s[threadIdx.x] - v;
}

__global__ __launch_bounds__(256) void k_add_off(
    int* __restrict__ rstart, const int* __restrict__ boff,
    int* __restrict__ cur, int N)
{
  const int i = blockIdx.x * 256 + threadIdx.x;
  if (i < N) {
    const int v = rstart[i] + boff[blockIdx.x];
    rstart[i] = v;
    cur[i] = v;
  }
}

__global__ __launch_bounds__(256) void k_fill(
    const int* __restrict__ esrc, const int* __restrict__ etgt,
    const int* __restrict__ erel, int* __restrict__ cur,
    int* __restrict__ packed)
{
  const int e = blockIdx.x * 256 + threadIdx.x;
  if (e < EE) {
    const int pos = atomicAdd(&cur[etgt[e]], 1);
    packed[pos] = esrc[e] | (erel[e] << 16);
  }
}

// ---------------------------------------------------------------------------
// Kernel 2: gather aggregation (unchanged from round 4).
// ---------------------------------------------------------------------------
__global__ __launch_bounds__(256) void k_agg(
    const unsigned short* __restrict__ P, const unsigned short* __restrict__ relb,
    const int* __restrict__ rstart, const int* __restrict__ packed,
    unsigned short* __restrict__ h_agg)
{
  const int node = blockIdx.x * 4 + (threadIdx.x >> 6);
  if (node >= NN) return;
  const int lane = threadIdx.x & 63;
  const int half = lane >> 5;
  const int c8   = (lane & 31) * 8;
  const int rc   = c8 & 127;

  const int beg = rstart[node];
  const int end = (node == NN - 1) ? EE : rstart[node + 1];

  float acc[8];
#pragma unroll
  for (int i = 0; i < 8; i++) acc[i] = 0.f;

  int j = beg + half;
  for (; j + 2 < end; j += 4) {
    const int p0 = packed[j];
    const int p1 = packed[j + 2];
    const bf16x8 pv0 = *(const bf16x8*)(P + (size_t)(p0 & 0xFFFF) * 256 + c8);
    const bf16x8 rv0 = *(const bf16x8*)(relb + (size_t)(p0 >> 16) * DD + rc);
    const bf16x8 pv1 = *(const bf16x8*)(P + (size_t)(p1 & 0xFFFF) * 256 + c8);
    const bf16x8 rv1 = *(const bf16x8*)(relb + (size_t)(p1 >> 16) * DD + rc);
#pragma unroll
    for (int i = 0; i < 8; i++) {
      acc[i] += bfbits(pv0[i]) * bfbits(rv0[i]);
      acc[i] += bfbits(pv1[i]) * bfbits(rv1[i]);
    }
  }
  for (; j < end; j += 2) {
    const int p0 = packed[j];
    const bf16x8 pv0 = *(const bf16x8*)(P + (size_t)(p0 & 0xFFFF) * 256 + c8);
    const bf16x8 rv0 = *(const bf16x8*)(relb + (size_t)(p0 >> 16) * DD + rc);
#pragma unroll
    for (int i = 0; i < 8; i++) acc[i] += bfbits(pv0[i]) * bfbits(rv0[i]);
  }

#pragma unroll
  for (int i = 0; i < 8; i++) acc[i] += __shfl_xor(acc[i], 32, 64);

  if (half == 0) {
    uint4 o;
    o.x = (unsigned int)f2bf(acc[0]) | ((unsigned int)f2bf(acc[1]) << 16);
    o.y = (unsigned int)f2bf(acc[2]) | ((unsigned int)f2bf(acc[3]) << 16);
    o.z = (unsigned int)f2bf(acc[4]) | ((unsigned int)f2bf(acc[5]) << 16);
    o.w = (unsigned int)f2bf(acc[6]) | ((unsigned int)f2bf(acc[7]) << 16);
    *(uint4*)(h_agg + (size_t)node * 256 + c8) = o;
  }
}

// ---------------------------------------------------------------------------
// Kernel 3: update GEMM (K=256), 32x32x16 MFMA, weights register-resident
// (64 VGPRs/lane). Features split across waves; LN partials combined through
// a 2KB LDS buffer (parity double-buffered, one barrier per tile).
// ---------------------------------------------------------------------------
__global__ __launch_bounds__(256) void k_update_ln(
    const float* __restrict__ h, const unsigned short* __restrict__ hb,
    const unsigned short* __restrict__ h_agg,
    const float* __restrict__ upd_W, const float* __restrict__ upd_b,
    const float* __restrict__ gamma, const float* __restrict__ beta,
    float* __restrict__ out, int BN)
{
  __shared__ float2 red[2][4][32];

  const int t    = threadIdx.x;
  const int w    = t >> 6;
  const int lane = t & 63;
  const int n32  = lane & 31;
  const int hi   = lane >> 5;
  const int f    = w * 32 + n32;

  // A-frags hoisted: A[m=f][k = 16ks + 8hi + j], K = 256
  FragU a[16];
#pragma unroll
  for (int ks = 0; ks < 16; ks++) {
#pragma unroll
    for (int j = 0; j < 8; j++) {
      const int k = ks * 16 + hi * 8 + j;
      a[ks].u[j] = f2bf(upd_W[k * DD + f]);
    }
  }

  const int nT = BN >> 5;
  int par = 0;
  for (int tile = blockIdx.x; tile < nT; tile += gridDim.x, par ^= 1) {
    const int row  = tile * 32 + n32;
    const int b    = (row >= NN) ? 1 : 0;
    const int node = row - b * NN;

    bf16x8 bf[16];
#pragma unroll
    for (int ks = 0; ks < 8; ks++)
      bf[ks] = *(const bf16x8*)(hb + (size_t)row * DD + ks * 16 + hi * 8);
#pragma unroll
    for (int ks = 8; ks < 16; ks++)
      bf[ks] = *(const bf16x8*)(h_agg + (size_t)node * 256 + b * 128 +
                                (ks - 8) * 16 + hi * 8);

    f32x16 acc = (f32x16)0.f;
#pragma unroll
    for (int ks = 0; ks < 16; ks++)
      acc = __builtin_amdgcn_mfma_f32_32x32x16_bf16(a[ks].v, bf[ks], acc, 0, 0, 0);

    // epilogue: x = h + relu(upd + bias); LN over f (cross-wave via LDS)
    float xv[16];
    float s1 = 0.f, s2 = 0.f;
#pragma unroll
    for (int q = 0; q < 4; q++) {
      const int f0 = w * 32 + q * 8 + hi * 4;
      const float4 bv = *(const float4*)(upd_b + f0);
      const float4 hv = *(const float4*)(h + (size_t)row * DD + f0);
      float x0 = hv.x + fmaxf(acc[q * 4 + 0] + bv.x, 0.f);
      float x1 = hv.y + fmaxf(acc[q * 4 + 1] + bv.y, 0.f);
      float x2 = hv.z + fmaxf(acc[q * 4 + 2] + bv.z, 0.f);
      float x3 = hv.w + fmaxf(acc[q * 4 + 3] + bv.w, 0.f);
      xv[q * 4 + 0] = x0; xv[q * 4 + 1] = x1;
      xv[q * 4 + 2] = x2; xv[q * 4 + 3] = x3;
      s1 += x0 + x1 + x2 + x3;
      s2 += x0 * x0 + x1 * x1 + x2 * x2 + x3 * x3;
    }
    s1 += __shfl_xor(s1, 32, 64);
    s2 += __shfl_xor(s2, 32, 64);
    if (hi == 0) red[par][w][n32] = float2{s1, s2};
    __syncthreads();
    float t1 = 0.f, t2 = 0.f;
#pragma unroll
    for (int ww = 0; ww < 4; ww++) {
      const float2 r = red[par][ww][n32];
      t1 += r.x; t2 += r.y;
    }
    const float mu   = t1 * (1.0f / DD);
    const float var  = t2 * (1.0f / DD) - mu * mu;
    const float rstd = rsqrtf(var + LN_EPS);

#pragma unroll
    for (int q = 0; q < 4; q++) {
      const int f0 = w * 32 + q * 8 + hi * 4;
      const float4 gv = *(const float4*)(gamma + f0);
      const float4 bt = *(const float4*)(beta + f0);
      float4 o;
      o.x = (xv[q * 4 + 0] - mu) * rstd * gv.x + bt.x;
      o.y = (xv[q * 4 + 1] - mu) * rstd * gv.y + bt.y;
      o.z = (xv[q * 4 + 2] - mu) * rstd * gv.z + bt.z;
      o.w = (xv[q * 4 + 3] - mu) * rstd * gv.w + bt.w;
      *(float4*)(out + (size_t)row * DD + f0) = o;
    }
  }
}

// ---------------------------------------------------------------------------
extern "C" void kernel_launch(void* const* d_in, const int* in_sizes, int n_in,
                              void* d_out, int out_size, void* d_ws, size_t ws_size,
                              hipStream_t stream) {
  const float* h       = (const float*)d_in[0];
  const int*   esrc    = (const int*)d_in[1];
  const int*   etgt    = (const int*)d_in[2];
  const int*   erel    = (const int*)d_in[3];
  const float* msg_W   = (const float*)d_in[5];
  const float* rel_emb = (const float*)d_in[6];
  const float* gate_W  = (const float*)d_in[7];
  const float* upd_W   = (const float*)d_in[8];
  const float* upd_b   = (const float*)d_in[9];
  const float* gamma   = (const float*)d_in[10];
  const float* beta    = (const float*)d_in[11];
  float*       out     = (float*)d_out;

  const int BN = in_sizes[0] / DD;   // 100000

  unsigned short* P     = (unsigned short*)d_ws;          // NN*256 bf16
  unsigned short* h_agg = P + (size_t)NN * 256;           // NN*256 bf16
  unsigned short* hb    = h_agg + (size_t)NN * 256;       // BN*128 bf16
  unsigned short* relb  = hb + (size_t)BN * DD;           // 500*128 bf16
  int* deg    = (int*)(relb + 500 * DD);
  int* rstart = deg + NN;
  int* cur    = rstart + NN;
  int* bsum   = cur + NN;
  int* boff   = bsum + 256;
  int* packed = boff + 256;                               // EE ints

  const int nbN = (NN + 255) / 256;
  const int nbE = (EE + 255) / 256;

  k_prep<<<nbN, 256, 0, stream>>>(rel_emb, relb, deg);

  k_node<<<512, 256, 0, stream>>>(h, gate_W, msg_W, P, hb, BN);

  k_hist<<<nbE, 256, 0, stream>>>(etgt, deg);
  k_scan_block<<<nbN, 256, 0, stream>>>(deg, rstart, bsum, NN);
  k_scan_small<<<1, 256, 0, stream>>>(bsum, boff, nbN);
  k_add_off<<<nbN, 256, 0, stream>>>(rstart, boff, cur, NN);
  k_fill<<<nbE, 256, 0, stream>>>(esrc, etgt, erel, cur, packed);

  k_agg<<<(NN + 3) / 4, 256, 0, stream>>>(P, relb, rstart, packed, h_agg);

  k_update_ln<<<512, 256, 0, stream>>>(h, hb, h_agg, upd_W, upd_b,
                                       gamma, beta, out, BN);
}

// Round 6
// 289.108 us; speedup vs baseline: 1.0907x; 1.0907x over previous
//
#include <hip/hip_runtime.h>

#define DD 128
#define NN 50000      // nodes (N)
#define BB 2          // batch
#define EE 500000     // edges
#define LN_EPS 1e-5f

typedef __attribute__((ext_vector_type(8))) short bf16x8;
typedef __attribute__((ext_vector_type(16))) float f32x16;

union FragU { unsigned short u[8]; bf16x8 v; };

__device__ __forceinline__ unsigned short f2bf(float x) {
  union { float f; unsigned u; } v; v.f = x;
  unsigned r = (v.u + 0x7FFFu + ((v.u >> 16) & 1u)) >> 16;
  return (unsigned short)r;
}
__device__ __forceinline__ float bfbits(short s) {
  union { unsigned u; float f; } v;
  v.u = ((unsigned)(unsigned short)s) << 16;
  return v.f;
}
__device__ __forceinline__ float sigmoidf(float x) {
  return 1.0f / (1.0f + __expf(-x));
}

// ---------------------------------------------------------------------------
// k_prep: zero deg + convert rel_emb fp32 -> bf16 (relb[r][128]).
// ---------------------------------------------------------------------------
__global__ __launch_bounds__(256) void k_prep(
    const float* __restrict__ rel_emb, unsigned short* __restrict__ relb,
    int* __restrict__ deg)
{
  const int id = blockIdx.x * 256 + threadIdx.x;
  if (id < 500 * DD / 2) {
    const float a = rel_emb[2 * id];
    const float b = rel_emb[2 * id + 1];
    *(unsigned int*)&relb[2 * id] =
        (unsigned int)f2bf(a) | ((unsigned int)f2bf(b) << 16);
  }
  if (id < NN) deg[id] = 0;
}

// ---------------------------------------------------------------------------
// Kernel 1: node dual-GEMM, 32x32x16 MFMA, weights register-resident.
// Wave w owns features [32w, 32w+32); A-frags hoisted into VGPRs.
// Epilogue: stage P tile in LDS (padded stride), then cooperative store with
// full-line coalescing (round-5 lesson: 64B-per-wave partial-line stores
// caused 3x write amplification; each line must be filled by one pass).
// ---------------------------------------------------------------------------
__global__ __launch_bounds__(256) void k_node(
    const float* __restrict__ h, const float* __restrict__ gate_W,
    const float* __restrict__ msg_W, unsigned short* __restrict__ P, int BN)
{
  __shared__ unsigned short Ps[32][132];   // 8448 B; stride 132 -> 2-way max

  const int t    = threadIdx.x;
  const int w    = t >> 6;        // wave -> feature strip [32w, 32w+32)
  const int lane = t & 63;
  const int n32  = lane & 31;
  const int hi   = lane >> 5;
  const int f    = w * 32 + n32;  // A-operand row m

  // ---- A-frags, hoisted: A[m=f][k = 16ks + 8hi + j] ----
  FragU ag[8], am[8];
#pragma unroll
  for (int ks = 0; ks < 8; ks++) {
#pragma unroll
    for (int j = 0; j < 8; j++) {
      const int k = ks * 16 + hi * 8 + j;
      ag[ks].u[j] = f2bf(gate_W[k * DD + f]);
      am[ks].u[j] = f2bf(msg_W [k * DD + f]);
    }
  }

  // store-phase constants
  const int nodeL = t >> 3;       // 0..31
  const int ch    = t & 7;        // 0..7 (16B chunks)

  const int nT = BN >> 5;   // 32-row tiles
  for (int tile = blockIdx.x; tile < nT; tile += gridDim.x) {
    const int row  = tile * 32 + n32;
    const size_t hoff = (size_t)row * DD + hi * 8;

    // B-frags: B[k][n=row], lane reads h[row][16ks + 8hi + 0..7]
    FragU bf[8];
#pragma unroll
    for (int ks = 0; ks < 8; ks++) {
      const float4 x0 = *(const float4*)(h + hoff + ks * 16);
      const float4 x1 = *(const float4*)(h + hoff + ks * 16 + 4);
      bf[ks].u[0] = f2bf(x0.x); bf[ks].u[1] = f2bf(x0.y);
      bf[ks].u[2] = f2bf(x0.z); bf[ks].u[3] = f2bf(x0.w);
      bf[ks].u[4] = f2bf(x1.x); bf[ks].u[5] = f2bf(x1.y);
      bf[ks].u[6] = f2bf(x1.z); bf[ks].u[7] = f2bf(x1.w);
    }

    f32x16 accg = (f32x16)0.f, accm = (f32x16)0.f;
#pragma unroll
    for (int ks = 0; ks < 8; ks++) {
      accg = __builtin_amdgcn_mfma_f32_32x32x16_bf16(ag[ks].v, bf[ks].v, accg, 0, 0, 0);
      accm = __builtin_amdgcn_mfma_f32_32x32x16_bf16(am[ks].v, bf[ks].v, accm, 0, 0, 0);
    }

    // stage into LDS: node n32, features f = 32w + 8q + 4hi + i
    unsigned short* Lr = &Ps[n32][w * 32 + hi * 4];
#pragma unroll
    for (int q = 0; q < 4; q++) {
      const float v0 = accm[q * 4 + 0] * sigmoidf(accg[q * 4 + 0]);
      const float v1 = accm[q * 4 + 1] * sigmoidf(accg[q * 4 + 1]);
      const float v2 = accm[q * 4 + 2] * sigmoidf(accg[q * 4 + 2]);
      const float v3 = accm[q * 4 + 3] * sigmoidf(accg[q * 4 + 3]);
      uint2 o;
      o.x = (unsigned int)f2bf(v0) | ((unsigned int)f2bf(v1) << 16);
      o.y = (unsigned int)f2bf(v2) | ((unsigned int)f2bf(v3) << 16);
      *(uint2*)(Lr + q * 8) = o;
    }
    __syncthreads();

    // coalesced store: thread t -> node = t>>3, 2 x 16B chunks, full lines
    const int grow = tile * 32 + nodeL;
    const int bS   = (grow >= NN) ? 1 : 0;
    unsigned short* gp = P + (size_t)(grow - bS * NN) * 256 + bS * 128;
    *(uint4*)(gp + ch * 8)       = *(uint4*)&Ps[nodeL][ch * 8];
    *(uint4*)(gp + (ch + 8) * 8) = *(uint4*)&Ps[nodeL][(ch + 8) * 8];
    __syncthreads();
  }
}

// ---------------------------------------------------------------------------
// CSR build: histogram -> block scans -> fill (counting sort by target).
// ---------------------------------------------------------------------------
__global__ __launch_bounds__(256) void k_hist(
    const int* __restrict__ etgt, int* __restrict__ deg)
{
  const int e = blockIdx.x * 256 + threadIdx.x;
  if (e < EE) atomicAdd(&deg[etgt[e]], 1);
}

__global__ __launch_bounds__(256) void k_scan_block(
    const int* __restrict__ deg, int* __restrict__ rstart,
    int* __restrict__ bsum, int N)
{
  __shared__ int s[256];
  const int i = blockIdx.x * 256 + threadIdx.x;
  const int v = (i < N) ? deg[i] : 0;
  s[threadIdx.x] = v;
  __syncthreads();
#pragma unroll
  for (int off = 1; off < 256; off <<= 1) {
    const int tv = (threadIdx.x >= off) ? s[threadIdx.x - off] : 0;
    __syncthreads();
    s[threadIdx.x] += tv;
    __syncthreads();
  }
  if (i < N) rstart[i] = s[threadIdx.x] - v;
  if (threadIdx.x == 255) bsum[blockIdx.x] = s[255];
}

__global__ __launch_bounds__(256) void k_scan_small(
    int* __restrict__ bsum, int* __restrict__ boff, int nb)
{
  __shared__ int s[256];
  const int v = (threadIdx.x < nb) ? bsum[threadIdx.x] : 0;
  s[threadIdx.x] = v;
  __syncthreads();
#pragma unroll
  for (int off = 1; off < 256; off <<= 1) {
    const int tv = (threadIdx.x >= off) ? s[threadIdx.x - off] : 0;
    __syncthreads();
    s[threadIdx.x] += tv;
    __syncthreads();
  }
  if (threadIdx.x < nb) boff[threadIdx.x] = s[threadIdx.x] - v;
}

__global__ __launch_bounds__(256) void k_add_off(
    int* __restrict__ rstart, const int* __restrict__ boff,
    int* __restrict__ cur, int N)
{
  const int i = blockIdx.x * 256 + threadIdx.x;
  if (i < N) {
    const int v = rstart[i] + boff[blockIdx.x];
    rstart[i] = v;
    cur[i] = v;
  }
}

__global__ __launch_bounds__(256) void k_fill(
    const int* __restrict__ esrc, const int* __restrict__ etgt,
    const int* __restrict__ erel, int* __restrict__ cur,
    int* __restrict__ packed)
{
  const int e = blockIdx.x * 256 + threadIdx.x;
  if (e < EE) {
    const int pos = atomicAdd(&cur[etgt[e]], 1);
    packed[pos] = esrc[e] | (erel[e] << 16);
  }
}

// ---------------------------------------------------------------------------
// Kernel 2: gather aggregation (unchanged).
// ---------------------------------------------------------------------------
__global__ __launch_bounds__(256) void k_agg(
    const unsigned short* __restrict__ P, const unsigned short* __restrict__ relb,
    const int* __restrict__ rstart, const int* __restrict__ packed,
    unsigned short* __restrict__ h_agg)
{
  const int node = blockIdx.x * 4 + (threadIdx.x >> 6);
  if (node >= NN) return;
  const int lane = threadIdx.x & 63;
  const int half = lane >> 5;
  const int c8   = (lane & 31) * 8;
  const int rc   = c8 & 127;

  const int beg = rstart[node];
  const int end = (node == NN - 1) ? EE : rstart[node + 1];

  float acc[8];
#pragma unroll
  for (int i = 0; i < 8; i++) acc[i] = 0.f;

  int j = beg + half;
  for (; j + 2 < end; j += 4) {
    const int p0 = packed[j];
    const int p1 = packed[j + 2];
    const bf16x8 pv0 = *(const bf16x8*)(P + (size_t)(p0 & 0xFFFF) * 256 + c8);
    const bf16x8 rv0 = *(const bf16x8*)(relb + (size_t)(p0 >> 16) * DD + rc);
    const bf16x8 pv1 = *(const bf16x8*)(P + (size_t)(p1 & 0xFFFF) * 256 + c8);
    const bf16x8 rv1 = *(const bf16x8*)(relb + (size_t)(p1 >> 16) * DD + rc);
#pragma unroll
    for (int i = 0; i < 8; i++) {
      acc[i] += bfbits(pv0[i]) * bfbits(rv0[i]);
      acc[i] += bfbits(pv1[i]) * bfbits(rv1[i]);
    }
  }
  for (; j < end; j += 2) {
    const int p0 = packed[j];
    const bf16x8 pv0 = *(const bf16x8*)(P + (size_t)(p0 & 0xFFFF) * 256 + c8);
    const bf16x8 rv0 = *(const bf16x8*)(relb + (size_t)(p0 >> 16) * DD + rc);
#pragma unroll
    for (int i = 0; i < 8; i++) acc[i] += bfbits(pv0[i]) * bfbits(rv0[i]);
  }

#pragma unroll
  for (int i = 0; i < 8; i++) acc[i] += __shfl_xor(acc[i], 32, 64);

  if (half == 0) {
    uint4 o;
    o.x = (unsigned int)f2bf(acc[0]) | ((unsigned int)f2bf(acc[1]) << 16);
    o.y = (unsigned int)f2bf(acc[2]) | ((unsigned int)f2bf(acc[3]) << 16);
    o.z = (unsigned int)f2bf(acc[4]) | ((unsigned int)f2bf(acc[5]) << 16);
    o.w = (unsigned int)f2bf(acc[6]) | ((unsigned int)f2bf(acc[7]) << 16);
    *(uint4*)(h_agg + (size_t)node * 256 + c8) = o;
  }
}

// ---------------------------------------------------------------------------
// Kernel 3: update GEMM (K=256), 32x32x16 MFMA, register weights.
// B-frags k<128 straight from fp32 h (converted in-register; the residual
// read of the same row hits L1), k>=128 from h_agg (bf16). Out stores are
// one full 128B line per node per wave (verified WRITE==logical in r5).
// ---------------------------------------------------------------------------
__global__ __launch_bounds__(256) void k_update_ln(
    const float* __restrict__ h, const unsigned short* __restrict__ h_agg,
    const float* __restrict__ upd_W, const float* __restrict__ upd_b,
    const float* __restrict__ gamma, const float* __restrict__ beta,
    float* __restrict__ out, int BN)
{
  __shared__ float2 red[2][4][32];

  const int t    = threadIdx.x;
  const int w    = t >> 6;
  const int lane = t & 63;
  const int n32  = lane & 31;
  const int hi   = lane >> 5;
  const int f    = w * 32 + n32;

  // A-frags hoisted: A[m=f][k = 16ks + 8hi + j], K = 256
  FragU a[16];
#pragma unroll
  for (int ks = 0; ks < 16; ks++) {
#pragma unroll
    for (int j = 0; j < 8; j++) {
      const int k = ks * 16 + hi * 8 + j;
      a[ks].u[j] = f2bf(upd_W[k * DD + f]);
    }
  }

  const int nT = BN >> 5;
  int par = 0;
  for (int tile = blockIdx.x; tile < nT; tile += gridDim.x, par ^= 1) {
    const int row  = tile * 32 + n32;
    const int b    = (row >= NN) ? 1 : 0;
    const int node = row - b * NN;

    bf16x8 bf[16];
#pragma unroll
    for (int ks = 0; ks < 8; ks++) {
      const float4 x0 = *(const float4*)(h + (size_t)row * DD + ks * 16 + hi * 8);
      const float4 x1 = *(const float4*)(h + (size_t)row * DD + ks * 16 + hi * 8 + 4);
      FragU u;
      u.u[0] = f2bf(x0.x); u.u[1] = f2bf(x0.y);
      u.u[2] = f2bf(x0.z); u.u[3] = f2bf(x0.w);
      u.u[4] = f2bf(x1.x); u.u[5] = f2bf(x1.y);
      u.u[6] = f2bf(x1.z); u.u[7] = f2bf(x1.w);
      bf[ks] = u.v;
    }
#pragma unroll
    for (int ks = 8; ks < 16; ks++)
      bf[ks] = *(const bf16x8*)(h_agg + (size_t)node * 256 + b * 128 +
                                (ks - 8) * 16 + hi * 8);

    f32x16 acc = (f32x16)0.f;
#pragma unroll
    for (int ks = 0; ks < 16; ks++)
      acc = __builtin_amdgcn_mfma_f32_32x32x16_bf16(a[ks].v, bf[ks], acc, 0, 0, 0);

    // epilogue: x = h + relu(upd + bias); LN over f (cross-wave via LDS)
    float xv[16];
    float s1 = 0.f, s2 = 0.f;
#pragma unroll
    for (int q = 0; q < 4; q++) {
      const int f0 = w * 32 + q * 8 + hi * 4;
      const float4 bv = *(const float4*)(upd_b + f0);
      const float4 hv = *(const float4*)(h + (size_t)row * DD + f0);
      float x0 = hv.x + fmaxf(acc[q * 4 + 0] + bv.x, 0.f);
      float x1 = hv.y + fmaxf(acc[q * 4 + 1] + bv.y, 0.f);
      float x2 = hv.z + fmaxf(acc[q * 4 + 2] + bv.z, 0.f);
      float x3 = hv.w + fmaxf(acc[q * 4 + 3] + bv.w, 0.f);
      xv[q * 4 + 0] = x0; xv[q * 4 + 1] = x1;
      xv[q * 4 + 2] = x2; xv[q * 4 + 3] = x3;
      s1 += x0 + x1 + x2 + x3;
      s2 += x0 * x0 + x1 * x1 + x2 * x2 + x3 * x3;
    }
    s1 += __shfl_xor(s1, 32, 64);
    s2 += __shfl_xor(s2, 32, 64);
    if (hi == 0) red[par][w][n32] = float2{s1, s2};
    __syncthreads();
    float t1 = 0.f, t2 = 0.f;
#pragma unroll
    for (int ww = 0; ww < 4; ww++) {
      const float2 r = red[par][ww][n32];
      t1 += r.x; t2 += r.y;
    }
    const float mu   = t1 * (1.0f / DD);
    const float var  = t2 * (1.0f / DD) - mu * mu;
    const float rstd = rsqrtf(var + LN_EPS);

#pragma unroll
    for (int q = 0; q < 4; q++) {
      const int f0 = w * 32 + q * 8 + hi * 4;
      const float4 gv = *(const float4*)(gamma + f0);
      const float4 bt = *(const float4*)(beta + f0);
      float4 o;
      o.x = (xv[q * 4 + 0] - mu) * rstd * gv.x + bt.x;
      o.y = (xv[q * 4 + 1] - mu) * rstd * gv.y + bt.y;
      o.z = (xv[q * 4 + 2] - mu) * rstd * gv.z + bt.z;
      o.w = (xv[q * 4 + 3] - mu) * rstd * gv.w + bt.w;
      *(float4*)(out + (size_t)row * DD + f0) = o;
    }
  }
}

// ---------------------------------------------------------------------------
extern "C" void kernel_launch(void* const* d_in, const int* in_sizes, int n_in,
                              void* d_out, int out_size, void* d_ws, size_t ws_size,
                              hipStream_t stream) {
  const float* h       = (const float*)d_in[0];
  const int*   esrc    = (const int*)d_in[1];
  const int*   etgt    = (const int*)d_in[2];
  const int*   erel    = (const int*)d_in[3];
  const float* msg_W   = (const float*)d_in[5];
  const float* rel_emb = (const float*)d_in[6];
  const float* gate_W  = (const float*)d_in[7];
  const float* upd_W   = (const float*)d_in[8];
  const float* upd_b   = (const float*)d_in[9];
  const float* gamma   = (const float*)d_in[10];
  const float* beta    = (const float*)d_in[11];
  float*       out     = (float*)d_out;

  const int BN = in_sizes[0] / DD;   // 100000

  unsigned short* P     = (unsigned short*)d_ws;          // NN*256 bf16
  unsigned short* h_agg = P + (size_t)NN * 256;           // NN*256 bf16
  unsigned short* relb  = h_agg + (size_t)NN * 256;       // 500*128 bf16
  int* deg    = (int*)(relb + 500 * DD);
  int* rstart = deg + NN;
  int* cur    = rstart + NN;
  int* bsum   = cur + NN;
  int* boff   = bsum + 256;
  int* packed = boff + 256;                               // EE ints

  const int nbN = (NN + 255) / 256;
  const int nbE = (EE + 255) / 256;

  k_prep<<<nbN, 256, 0, stream>>>(rel_emb, relb, deg);

  k_node<<<1024, 256, 0, stream>>>(h, gate_W, msg_W, P, BN);

  k_hist<<<nbE, 256, 0, stream>>>(etgt, deg);
  k_scan_block<<<nbN, 256, 0, stream>>>(deg, rstart, bsum, NN);
  k_scan_small<<<1, 256, 0, stream>>>(bsum, boff, nbN);
  k_add_off<<<nbN, 256, 0, stream>>>(rstart, boff, cur, NN);
  k_fill<<<nbE, 256, 0, stream>>>(esrc, etgt, erel, cur, packed);

  k_agg<<<(NN + 3) / 4, 256, 0, stream>>>(P, relb, rstart, packed, h_agg);

  k_update_ln<<<512, 256, 0, stream>>>(h, h_agg, upd_W, upd_b,
                                       gamma, beta, out, BN);
}